// Round 4
// 635.388 us; speedup vs baseline: 1.0854x; 1.0854x over previous
//
#include <hip/hip_runtime.h>

#define NG 4096       // graphs
#define NN 524288     // nodes
#define H  128        // hidden
#define H2 256        // 2*H

typedef __attribute__((ext_vector_type(8))) short bf16x8;
typedef __attribute__((ext_vector_type(4))) float floatx4;
typedef __attribute__((ext_vector_type(2))) unsigned int uint2v;
typedef __attribute__((ext_vector_type(4))) unsigned int uint4v;

__device__ __forceinline__ unsigned short bf16r(float f) {
    unsigned int u = __builtin_bit_cast(unsigned int, f);
    u += 0x7fffu + ((u >> 16) & 1u);          // RNE truncate to bf16
    return (unsigned short)(u >> 16);
}
__device__ __forceinline__ unsigned int bf16pk2(float a, float b) {
    return (unsigned int)bf16r(a) | ((unsigned int)bf16r(b) << 16);
}

// ---------------------------------------------------------------------------
// Kernel 1: segment sum, streaming + atomics, float4 (16 B/lane) loads.
// 256 thr = 8 chains x 32 lanes; each chain owns 32 contiguous rows, lane
// owns 4 columns. Sorted segment_ids -> boundaries rare & chain-uniform;
// atomicAdd only at boundaries. agg must be pre-zeroed.
// ---------------------------------------------------------------------------
#define SS_ROWS 256
#define SS_CH   8
#define SS_LEN  (SS_ROWS / SS_CH)   // 32 rows per chain

__global__ __launch_bounds__(256) void seg_sum_atomic(
    const float* __restrict__ node, const int* __restrict__ seg,
    float* __restrict__ agg) {
    const int c4   = (threadIdx.x & 31) * 4;
    const int base = blockIdx.x * SS_ROWS + (threadIdx.x >> 5) * SS_LEN;

    floatx4 acc = {0.f, 0.f, 0.f, 0.f};
    int cur = seg[base];
    #pragma unroll 4
    for (int r = 0; r < SS_LEN; ++r) {
        const int row = base + r;
        const int sgv = seg[row];
        const floatx4 v = *(const floatx4*)(node + (size_t)row * H + c4);
        if (sgv != cur) {                      // chain-uniform branch
            float* a = &agg[(size_t)cur * H + c4];
            atomicAdd(a + 0, acc[0]); atomicAdd(a + 1, acc[1]);
            atomicAdd(a + 2, acc[2]); atomicAdd(a + 3, acc[3]);
            acc = (floatx4){0.f, 0.f, 0.f, 0.f};
            cur = sgv;
        }
        acc += v;
    }
    float* a = &agg[(size_t)cur * H + c4];
    atomicAdd(a + 0, acc[0]); atomicAdd(a + 1, acc[1]);
    atomicAdd(a + 2, acc[2]); atomicAdd(a + 3, acc[3]);
}

// ---------------------------------------------------------------------------
// Kernel 2+3: fused 2-layer MLP via bf16 MFMA, weight-stationary.
//   out = relu(relu([in0[row], in1(gather(row))] @ W1 + b1) @ W2 + b2)
// Block = 256 thr = 4 waves; wave w owns output feats [32w,32w+32).
// The 16x256 input tile is staged COOPERATIVELY: each thread loads+packs 16
// elems (1/4 of the old per-wave redundant work) into a padded bf16 LDS tile
// (row stride 264 shorts -> conflict-free b128 R/W), and all waves read
// B-frags from LDS. Next tile's global loads issue right after barrier1 so
// HBM/gather latency hides under both GEMMs.
// Double-buffered ldsB, single ldsH, 2 barriers/tile.
// ---------------------------------------------------------------------------
#define BSTR 264   // ldsB row stride in shorts (256 + 8 pad)

template<int TILES_, bool GATHER, bool NT>
__global__ __launch_bounds__(256) void mlp_mfma(
    const float* __restrict__ in0, const int* __restrict__ seg,
    const float* __restrict__ in1,
    const float* __restrict__ W1, const float* __restrict__ b1,
    const float* __restrict__ W2, const float* __restrict__ b2,
    float* __restrict__ outp) {

    __shared__ unsigned short ldsB[2][16 * BSTR];  // [buf][row][k] bf16, K=256
    __shared__ unsigned short ldsH[16 * 136];      // [row][feat] bf16, pad->136

    const int tid   = threadIdx.x;
    const int wid   = tid >> 6;
    const int lane  = tid & 63;
    const int l16   = lane & 15;
    const int quad  = lane >> 4;
    const int fbase = wid * 32;
    // staging coords: thread owns row sr, 16-float chunk sc
    const int sr = tid >> 4;      // 0..15
    const int sc = tid & 15;      // 0..15  (sc<8 -> in0, sc>=8 -> in1)

    // ---- stationary weights: A[m=lane&15][k=quad*8+j] = W[k][m] ----
    bf16x8 A1[2][8];
    #pragma unroll
    for (int mt = 0; mt < 2; ++mt)
        #pragma unroll
        for (int kt = 0; kt < 8; ++kt) {
            const float* b = W1 + (size_t)(kt * 32 + quad * 8) * H
                                + fbase + mt * 16 + l16;
            union { unsigned int u[4]; bf16x8 v; } r;
            #pragma unroll
            for (int j = 0; j < 4; ++j)
                r.u[j] = bf16pk2(b[(2 * j) * H], b[(2 * j + 1) * H]);
            A1[mt][kt] = r.v;
        }
    bf16x8 A2[2][4];
    #pragma unroll
    for (int mt = 0; mt < 2; ++mt)
        #pragma unroll
        for (int kt = 0; kt < 4; ++kt) {
            const float* b = W2 + (size_t)(kt * 32 + quad * 8) * H
                                + fbase + mt * 16 + l16;
            union { unsigned int u[4]; bf16x8 v; } r;
            #pragma unroll
            for (int j = 0; j < 4; ++j)
                r.u[j] = bf16pk2(b[(2 * j) * H], b[(2 * j + 1) * H]);
            A2[mt][kt] = r.v;
        }
    floatx4 b1v[2], b2v[2];
    #pragma unroll
    for (int mt = 0; mt < 2; ++mt) {
        b1v[mt] = *(const floatx4*)(b1 + fbase + mt * 16 + quad * 4);
        b2v[mt] = *(const floatx4*)(b2 + fbase + mt * 16 + quad * 4);
    }

    const int nb0 = blockIdx.x * (TILES_ * 16);

    floatx4 pf[4];   // 16 staged floats / thread

    auto stage_load = [&](int t) {
        const int row = nb0 + t * 16 + sr;
        const float* p;
        if (sc < 8) {
            p = in0 + (size_t)row * H + sc * 16;
        } else {
            const int g = GATHER ? seg[row] : row;
            p = in1 + (size_t)g * H + (sc - 8) * 16;
        }
        #pragma unroll
        for (int i = 0; i < 4; ++i)
            pf[i] = *(const floatx4*)(p + i * 4);
    };
    auto stage_write = [&](int buf) {
        unsigned short* d = &ldsB[buf][sr * BSTR + sc * 16];
        uint4v w0 = (uint4v){ bf16pk2(pf[0][0], pf[0][1]), bf16pk2(pf[0][2], pf[0][3]),
                              bf16pk2(pf[1][0], pf[1][1]), bf16pk2(pf[1][2], pf[1][3]) };
        uint4v w1 = (uint4v){ bf16pk2(pf[2][0], pf[2][1]), bf16pk2(pf[2][2], pf[2][3]),
                              bf16pk2(pf[3][0], pf[3][1]), bf16pk2(pf[3][2], pf[3][3]) };
        *(uint4v*)d = w0;
        *(uint4v*)(d + 8) = w1;
    };

    // ---- prologue: stage tile 0 ----
    stage_load(0);
    stage_write(0);

    for (int t = 0; t < TILES_; ++t) {
        __syncthreads();                       // ldsB[t&1] visible
        if (t + 1 < TILES_) stage_load(t + 1); // issue next tile's global loads NOW

        // ---- GEMM1: K=256 from ldsB ----
        floatx4 acc1[2];
        acc1[0] = (floatx4){0.f, 0.f, 0.f, 0.f};
        acc1[1] = (floatx4){0.f, 0.f, 0.f, 0.f};
        const unsigned short* bsrc = &ldsB[t & 1][0];
        #pragma unroll
        for (int kt = 0; kt < 8; ++kt) {
            bf16x8 bf = *(const bf16x8*)(bsrc + l16 * BSTR + kt * 32 + quad * 8);
            acc1[0] = __builtin_amdgcn_mfma_f32_16x16x32_bf16(A1[0][kt], bf, acc1[0], 0, 0, 0);
            acc1[1] = __builtin_amdgcn_mfma_f32_16x16x32_bf16(A1[1][kt], bf, acc1[1], 0, 0, 0);
        }
        // bias + relu + pack -> ldsH
        #pragma unroll
        for (int mt = 0; mt < 2; ++mt) {
            floatx4 v = acc1[mt] + b1v[mt];
            uint2v u;
            u[0] = bf16pk2(fmaxf(v[0], 0.f), fmaxf(v[1], 0.f));
            u[1] = bf16pk2(fmaxf(v[2], 0.f), fmaxf(v[3], 0.f));
            *(uint2v*)&ldsH[l16 * 136 + fbase + mt * 16 + quad * 4] = u;
        }
        // pack + write next tile's staged regs into the other B buffer
        if (t + 1 < TILES_) stage_write((t + 1) & 1);

        __syncthreads();                       // ldsH (and ldsB[(t+1)&1]) visible

        // ---- GEMM2: K=128 from ldsH ----
        floatx4 acc2[2];
        acc2[0] = (floatx4){0.f, 0.f, 0.f, 0.f};
        acc2[1] = (floatx4){0.f, 0.f, 0.f, 0.f};
        #pragma unroll
        for (int kt = 0; kt < 4; ++kt) {
            bf16x8 bf = *(const bf16x8*)&ldsH[l16 * 136 + kt * 32 + quad * 8];
            acc2[0] = __builtin_amdgcn_mfma_f32_16x16x32_bf16(A2[0][kt], bf, acc2[0], 0, 0, 0);
            acc2[1] = __builtin_amdgcn_mfma_f32_16x16x32_bf16(A2[1][kt], bf, acc2[1], 0, 0, 0);
        }
        // ---- bias + relu + direct C-layout store ----
        const int nb = nb0 + t * 16;
        #pragma unroll
        for (int mt = 0; mt < 2; ++mt) {
            floatx4 v = acc2[mt] + b2v[mt];
            floatx4 o;
            o[0] = fmaxf(v[0], 0.f); o[1] = fmaxf(v[1], 0.f);
            o[2] = fmaxf(v[2], 0.f); o[3] = fmaxf(v[3], 0.f);
            float* dst = outp + (size_t)(nb + l16) * H + fbase + mt * 16 + quad * 4;
            if (NT) __builtin_nontemporal_store(o, (floatx4*)dst);
            else    *(floatx4*)dst = o;
        }
    }
}

extern "C" void kernel_launch(void* const* d_in, const int* in_sizes, int n_in,
                              void* d_out, int out_size, void* d_ws, size_t ws_size,
                              hipStream_t stream) {
    const float* updated_set  = (const float*)d_in[0];   // [G,H]
    const float* updated_node = (const float*)d_in[1];   // [N,H]
    const int*   segment_ids  = (const int*)  d_in[2];   // [N]
    const float* Ws1 = (const float*)d_in[3];            // [2H,H]
    const float* bs1 = (const float*)d_in[4];            // [H]
    const float* Ws2 = (const float*)d_in[5];            // [H,H]
    const float* bs2 = (const float*)d_in[6];            // [H]
    const float* Wn1 = (const float*)d_in[7];            // [2H,H]
    const float* bn1 = (const float*)d_in[8];            // [H]
    const float* Wn2 = (const float*)d_in[9];            // [H,H]
    const float* bn2 = (const float*)d_in[10];           // [H]

    float* s_out = (float*)d_out;                        // [G,H]
    float* n_out = (float*)d_out + (size_t)NG * H;       // [N,H]
    float* agg   = (float*)d_ws;                         // [G,H] scratch

    // agg := 0 (d_ws is poisoned 0xAA before every call)
    hipMemsetAsync(agg, 0, (size_t)NG * H * sizeof(float), stream);

    seg_sum_atomic<<<NN / SS_ROWS, 256, 0, stream>>>(updated_node, segment_ids, agg);

    // set MLP: rows = agg ++ updated_set (identity gather), cached stores
    mlp_mfma<1, false, false><<<NG / 16, 256, 0, stream>>>(
        agg, nullptr, updated_set, Ws1, bs1, Ws2, bs2, s_out);

    // node MLP: rows = node ++ s[seg], nontemporal stores, 16 tiles/block
    mlp_mfma<16, true, true><<<NN / (16 * 16), 256, 0, stream>>>(
        updated_node, segment_ids, s_out, Wn1, bn1, Wn2, bn2, n_out);
}

// Round 5
// 613.918 us; speedup vs baseline: 1.1234x; 1.0350x over previous
//
#include <hip/hip_runtime.h>

#define NG 4096       // graphs
#define NN 524288     // nodes
#define H  128        // hidden
#define H2 256        // 2*H

typedef __attribute__((ext_vector_type(8))) short bf16x8;
typedef __attribute__((ext_vector_type(4))) float floatx4;
typedef __attribute__((ext_vector_type(2))) unsigned int uint2v;
typedef __attribute__((ext_vector_type(4))) unsigned int uint4v;

// RNE f32x2 -> packed bf16x2 in one VALU op (gfx950; verified learn_hip m214v22)
__device__ __forceinline__ unsigned int cvtpk2(float a, float b) {
    unsigned int r;
    asm("v_cvt_pk_bf16_f32 %0, %1, %2" : "=v"(r) : "v"(a), "v"(b));
    return r;
}

// ---------------------------------------------------------------------------
// Kernel 1: segment sum, streaming + atomics, float4 (16 B/lane) loads.
// 256 thr = 8 chains x 32 lanes; chain owns 32 contiguous rows, lane owns 4
// cols. Sorted segment_ids -> boundaries rare & chain-uniform; atomicAdd only
// at boundaries. agg must be pre-zeroed.
// ---------------------------------------------------------------------------
#define SS_ROWS 256
#define SS_CH   8
#define SS_LEN  (SS_ROWS / SS_CH)   // 32 rows per chain

__global__ __launch_bounds__(256) void seg_sum_atomic(
    const float* __restrict__ node, const int* __restrict__ seg,
    float* __restrict__ agg) {
    const int c4   = (threadIdx.x & 31) * 4;
    const int base = blockIdx.x * SS_ROWS + (threadIdx.x >> 5) * SS_LEN;

    floatx4 acc = {0.f, 0.f, 0.f, 0.f};
    int cur = seg[base];
    #pragma unroll 4
    for (int r = 0; r < SS_LEN; ++r) {
        const int row = base + r;
        const int sgv = seg[row];
        const floatx4 v = *(const floatx4*)(node + (size_t)row * H + c4);
        if (sgv != cur) {                      // chain-uniform branch
            float* a = &agg[(size_t)cur * H + c4];
            atomicAdd(a + 0, acc[0]); atomicAdd(a + 1, acc[1]);
            atomicAdd(a + 2, acc[2]); atomicAdd(a + 3, acc[3]);
            acc = (floatx4){0.f, 0.f, 0.f, 0.f};
            cur = sgv;
        }
        acc += v;
    }
    float* a = &agg[(size_t)cur * H + c4];
    atomicAdd(a + 0, acc[0]); atomicAdd(a + 1, acc[1]);
    atomicAdd(a + 2, acc[2]); atomicAdd(a + 3, acc[3]);
}

// ---------------------------------------------------------------------------
// Kernel 2+3: fused 2-layer MLP via bf16 MFMA, weight-stationary.
//   out = relu(relu([in0[row], in1(gather(row))] @ W1 + b1) @ W2 + b2)
// Block = 256 thr = 4 waves; wave w owns output feats [32w,32w+32).
// Staging: thread (sr=tid>>4, sc=tid&15) owns elements [8sc,8sc+8) of in0 row
// sr AND of the gathered in1 row -> LDS slots sc and sc+16 (16B each).
//   - global side: 16 lanes x 32 B = fully contiguous 512 B per row
//   - LDS write groups hit slot-mod-8 residues uniformly -> 2-way (free),
//     fixing the previous 4-way stage_write conflict (9.4M conflict cycles)
// Depth-2 prefetch (T14 issue-early/write-late): at tile t, LDS-write tile
// t+1's regs (loaded at t-1: full tile of latency cover) and issue t+2's
// global loads. Two statically-indexed reg sets (pfA/pfB), 2 barriers/tile.
// Pack via v_cvt_pk_bf16_f32 (1 op / 2 elems). Plain (non-NT) stores: NT 64B
// half-line stores caused +110 MB write amplification (378 vs 268 MB).
// ---------------------------------------------------------------------------
#define BSTR 264   // ldsB row stride in shorts (33 slots of 16 B; odd -> clean banks)

template<int TILES_, bool GATHER, bool NT>
__global__ __launch_bounds__(256) void mlp_mfma(
    const float* __restrict__ in0, const int* __restrict__ seg,
    const float* __restrict__ in1,
    const float* __restrict__ W1, const float* __restrict__ b1,
    const float* __restrict__ W2, const float* __restrict__ b2,
    float* __restrict__ outp) {

    __shared__ unsigned short ldsB[2][16 * BSTR];  // [buf][row][k] bf16, K=256
    __shared__ unsigned short ldsH[16 * 136];      // [row][feat] bf16, pad->136

    const int tid   = threadIdx.x;
    const int wid   = tid >> 6;
    const int lane  = tid & 63;
    const int l16   = lane & 15;
    const int quad  = lane >> 4;
    const int fbase = wid * 32;
    const int sr    = tid >> 4;   // staging row 0..15
    const int sc    = tid & 15;   // staging slot 0..15 (elements 8sc..8sc+7)

    // ---- stationary weights: A[m=lane&15][k=quad*8+j] = W[k][m] ----
    bf16x8 A1[2][8];
    #pragma unroll
    for (int mt = 0; mt < 2; ++mt)
        #pragma unroll
        for (int kt = 0; kt < 8; ++kt) {
            const float* b = W1 + (size_t)(kt * 32 + quad * 8) * H
                                + fbase + mt * 16 + l16;
            union { unsigned int u[4]; bf16x8 v; } r;
            #pragma unroll
            for (int j = 0; j < 4; ++j)
                r.u[j] = cvtpk2(b[(2 * j) * H], b[(2 * j + 1) * H]);
            A1[mt][kt] = r.v;
        }
    bf16x8 A2[2][4];
    #pragma unroll
    for (int mt = 0; mt < 2; ++mt)
        #pragma unroll
        for (int kt = 0; kt < 4; ++kt) {
            const float* b = W2 + (size_t)(kt * 32 + quad * 8) * H
                                + fbase + mt * 16 + l16;
            union { unsigned int u[4]; bf16x8 v; } r;
            #pragma unroll
            for (int j = 0; j < 4; ++j)
                r.u[j] = cvtpk2(b[(2 * j) * H], b[(2 * j + 1) * H]);
            A2[mt][kt] = r.v;
        }
    floatx4 b1v[2], b2v[2];
    #pragma unroll
    for (int mt = 0; mt < 2; ++mt) {
        b1v[mt] = *(const floatx4*)(b1 + fbase + mt * 16 + quad * 4);
        b2v[mt] = *(const floatx4*)(b2 + fbase + mt * 16 + quad * 4);
    }

    const int nb0 = blockIdx.x * (TILES_ * 16);

    floatx4 pfA[4], pfB[4];   // [0..1]: in0 8 floats; [2..3]: in1 8 floats

#define STAGE_LOAD(T, PF) do {                                                \
    const int row_ = nb0 + (T) * 16 + sr;                                     \
    const float* p0_ = in0 + (size_t)row_ * H + sc * 8;                       \
    PF[0] = *(const floatx4*)(p0_);                                           \
    PF[1] = *(const floatx4*)(p0_ + 4);                                       \
    const int g_ = GATHER ? seg[row_] : row_;                                 \
    const float* p1_ = in1 + (size_t)g_ * H + sc * 8;                         \
    PF[2] = *(const floatx4*)(p1_);                                           \
    PF[3] = *(const floatx4*)(p1_ + 4);                                       \
} while (0)

#define STAGE_WRITE(BUF, PF) do {                                             \
    unsigned short* d_ = &ldsB[BUF][sr * BSTR + sc * 8];                      \
    *(uint4v*)d_ = (uint4v){ cvtpk2(PF[0][0], PF[0][1]),                      \
                             cvtpk2(PF[0][2], PF[0][3]),                      \
                             cvtpk2(PF[1][0], PF[1][1]),                      \
                             cvtpk2(PF[1][2], PF[1][3]) };                    \
    *(uint4v*)(d_ + 128) = (uint4v){ cvtpk2(PF[2][0], PF[2][1]),              \
                                     cvtpk2(PF[2][2], PF[2][3]),              \
                                     cvtpk2(PF[3][0], PF[3][1]),              \
                                     cvtpk2(PF[3][2], PF[3][3]) };            \
} while (0)

    // Per-tile body: consumes ldsB[T&1]; LDS-writes PFW (tile T+1) into the
    // other buffer; issues tile T+2's global loads into PFL.
#define TILE_BODY(T, PFW, PFL) do {                                           \
    __syncthreads();  /* ldsB[(T)&1] (written at T-1) + ldsH(T-1) consumed */ \
    if ((T) + 1 < TILES_) STAGE_WRITE(((T) + 1) & 1, PFW);                    \
    if ((T) + 2 < TILES_) STAGE_LOAD((T) + 2, PFL);                           \
    floatx4 acc1[2];                                                          \
    acc1[0] = (floatx4){0.f, 0.f, 0.f, 0.f};                                  \
    acc1[1] = (floatx4){0.f, 0.f, 0.f, 0.f};                                  \
    const unsigned short* bsrc_ = &ldsB[(T) & 1][0];                          \
    _Pragma("unroll")                                                         \
    for (int kt = 0; kt < 8; ++kt) {                                          \
        bf16x8 bf = *(const bf16x8*)(bsrc_ + l16 * BSTR + kt * 32 + quad * 8);\
        acc1[0] = __builtin_amdgcn_mfma_f32_16x16x32_bf16(A1[0][kt], bf, acc1[0], 0, 0, 0); \
        acc1[1] = __builtin_amdgcn_mfma_f32_16x16x32_bf16(A1[1][kt], bf, acc1[1], 0, 0, 0); \
    }                                                                         \
    _Pragma("unroll")                                                         \
    for (int mt = 0; mt < 2; ++mt) {                                          \
        floatx4 v = acc1[mt] + b1v[mt];                                       \
        uint2v u;                                                             \
        u[0] = cvtpk2(fmaxf(v[0], 0.f), fmaxf(v[1], 0.f));                    \
        u[1] = cvtpk2(fmaxf(v[2], 0.f), fmaxf(v[3], 0.f));                    \
        *(uint2v*)&ldsH[l16 * 136 + fbase + mt * 16 + quad * 4] = u;          \
    }                                                                         \
    __syncthreads();  /* ldsH visible */                                      \
    floatx4 acc2[2];                                                          \
    acc2[0] = (floatx4){0.f, 0.f, 0.f, 0.f};                                  \
    acc2[1] = (floatx4){0.f, 0.f, 0.f, 0.f};                                  \
    _Pragma("unroll")                                                         \
    for (int kt = 0; kt < 4; ++kt) {                                          \
        bf16x8 bf = *(const bf16x8*)&ldsH[l16 * 136 + kt * 32 + quad * 8];    \
        acc2[0] = __builtin_amdgcn_mfma_f32_16x16x32_bf16(A2[0][kt], bf, acc2[0], 0, 0, 0); \
        acc2[1] = __builtin_amdgcn_mfma_f32_16x16x32_bf16(A2[1][kt], bf, acc2[1], 0, 0, 0); \
    }                                                                         \
    const int nb_ = nb0 + (T) * 16;                                           \
    _Pragma("unroll")                                                         \
    for (int mt = 0; mt < 2; ++mt) {                                          \
        floatx4 v = acc2[mt] + b2v[mt];                                       \
        floatx4 o;                                                            \
        o[0] = fmaxf(v[0], 0.f); o[1] = fmaxf(v[1], 0.f);                     \
        o[2] = fmaxf(v[2], 0.f); o[3] = fmaxf(v[3], 0.f);                     \
        float* dst_ = outp + (size_t)(nb_ + l16) * H + fbase + mt * 16 + quad * 4; \
        if (NT) __builtin_nontemporal_store(o, (floatx4*)dst_);               \
        else    *(floatx4*)dst_ = o;                                          \
    }                                                                         \
} while (0)

    // ---- prologue: tile0 staged to LDS; tile1 staged to regs ----
    STAGE_LOAD(0, pfA);
    STAGE_WRITE(0, pfA);
    if (TILES_ > 1) STAGE_LOAD(1, pfB);

    for (int t = 0; t < TILES_; t += 2) {
        TILE_BODY(t, pfB, pfA);                    // even tile: write pfB, load->pfA
        if (t + 1 < TILES_) TILE_BODY(t + 1, pfA, pfB);  // odd: write pfA, load->pfB
    }

#undef STAGE_LOAD
#undef STAGE_WRITE
#undef TILE_BODY
}

extern "C" void kernel_launch(void* const* d_in, const int* in_sizes, int n_in,
                              void* d_out, int out_size, void* d_ws, size_t ws_size,
                              hipStream_t stream) {
    const float* updated_set  = (const float*)d_in[0];   // [G,H]
    const float* updated_node = (const float*)d_in[1];   // [N,H]
    const int*   segment_ids  = (const int*)  d_in[2];   // [N]
    const float* Ws1 = (const float*)d_in[3];            // [2H,H]
    const float* bs1 = (const float*)d_in[4];            // [H]
    const float* Ws2 = (const float*)d_in[5];            // [H,H]
    const float* bs2 = (const float*)d_in[6];            // [H]
    const float* Wn1 = (const float*)d_in[7];            // [2H,H]
    const float* bn1 = (const float*)d_in[8];            // [H]
    const float* Wn2 = (const float*)d_in[9];            // [H,H]
    const float* bn2 = (const float*)d_in[10];           // [H]

    float* s_out = (float*)d_out;                        // [G,H]
    float* n_out = (float*)d_out + (size_t)NG * H;       // [N,H]
    float* agg   = (float*)d_ws;                         // [G,H] scratch

    // agg := 0 (d_ws is poisoned 0xAA before every call)
    hipMemsetAsync(agg, 0, (size_t)NG * H * sizeof(float), stream);

    seg_sum_atomic<<<NN / SS_ROWS, 256, 0, stream>>>(updated_node, segment_ids, agg);

    // set MLP: rows = agg ++ updated_set (identity gather)
    mlp_mfma<1, false, false><<<NG / 16, 256, 0, stream>>>(
        agg, nullptr, updated_set, Ws1, bs1, Ws2, bs2, s_out);

    // node MLP: rows = node ++ s[seg]; plain stores (NT caused write-amp)
    mlp_mfma<16, true, false><<<NN / (16 * 16), 256, 0, stream>>>(
        updated_node, segment_ids, s_out, Wn1, bn1, Wn2, bn2, n_out);
}